// Round 9
// baseline (774.084 us; speedup 1.0000x reference)
//
#include <hip/hip_runtime.h>
#include <math.h>

#define TT 10
#define BB 32
#define CIN 3
#define COUT 64
#define HH 64
#define WW 64
#define HW (HH*WW)           // 4096
#define DECAY 0.2f
#define INH 1.625f

__device__ __forceinline__ unsigned int enc_f(float f) {
    unsigned int u = __float_as_uint(f);
    return (u & 0x80000000u) ? ~u : (u | 0x80000000u);
}
__device__ __forceinline__ float dec_f(unsigned int u) {
    u = (u & 0x80000000u) ? (u & 0x7FFFFFFFu) : ~u;
    return __uint_as_float(u);
}

// ---------------------------------------------------------------------------
// Pass 1: thr[t][c] = max over (B,H,W) of conv. t-parallel.
// r8's conv recipe: lane=channel, W[27] per-lane VGPRs, x window from LDS via
// wave-uniform broadcast vector reads. i is NOT stored (threshold only).
// Grid (16 rowgroups, B, T) x 256 (wave = one row).
// ---------------------------------------------------------------------------
__global__ __launch_bounds__(256) void thr_kernel(
    const float* __restrict__ x,        // (T,B,3,64,64)
    const float* __restrict__ Wt,       // (64,3,3,3)
    unsigned int* __restrict__ thr_raw) // (T,64) pre-zeroed
{
    __shared__ float sx[CIN][6][68];    // stride 68 -> 16B-aligned rows
    __shared__ float wmax[4][COUT];

    const int tid  = threadIdx.x;
    const int lane = tid & 63;          // channel
    const int wave = tid >> 6;          // row within 4-row group
    const int h0   = blockIdx.x * 4;
    const int b    = blockIdx.y;
    const int t    = blockIdx.z;

    float w[27];
    #pragma unroll
    for (int k = 0; k < 27; k++) w[k] = Wt[lane * 27 + k];

    const float* xb = x + ((size_t)t * BB + b) * (CIN * HW);
    for (int l = tid; l < CIN * 6 * 66; l += 256) {
        int ci  = l / 396;
        int r   = (l % 396) / 66;
        int col = l % 66;
        int gh = h0 + r - 1;
        int gw = col - 1;
        float v = 0.f;
        if (gh >= 0 && gh < HH && gw >= 0 && gw < WW)
            v = xb[ci * HW + gh * WW + gw];
        sx[ci][r][col] = v;
    }
    __syncthreads();

    float mx = -INFINITY;

    for (int cc = 0; cc < 16; cc++) {          // 4-pixel chunks
        float acc0 = 0.f, acc1 = 0.f, acc2 = 0.f, acc3 = 0.f;
        #pragma unroll
        for (int ci = 0; ci < CIN; ci++)
            #pragma unroll
            for (int kh = 0; kh < 3; kh++) {
                const float* rp = &sx[ci][wave + kh][cc * 4];
                float4 q  = *(const float4*)rp;          // broadcast b128
                float2 r2 = *(const float2*)(rp + 4);    // broadcast b64
                float x0 = q.x, x1 = q.y, x2 = q.z, x3 = q.w;
                float x4 = r2.x, x5 = r2.y;
                const float w0 = w[ci * 9 + kh * 3 + 0];
                const float w1 = w[ci * 9 + kh * 3 + 1];
                const float w2 = w[ci * 9 + kh * 3 + 2];
                acc0 = fmaf(w0, x0, acc0); acc0 = fmaf(w1, x1, acc0); acc0 = fmaf(w2, x2, acc0);
                acc1 = fmaf(w0, x1, acc1); acc1 = fmaf(w1, x2, acc1); acc1 = fmaf(w2, x3, acc1);
                acc2 = fmaf(w0, x2, acc2); acc2 = fmaf(w1, x3, acc2); acc2 = fmaf(w2, x4, acc2);
                acc3 = fmaf(w0, x3, acc3); acc3 = fmaf(w1, x4, acc3); acc3 = fmaf(w2, x5, acc3);
            }
        mx = fmaxf(mx, fmaxf(fmaxf(acc0, acc1), fmaxf(acc2, acc3)));
    }

    wmax[wave][lane] = mx;
    __syncthreads();
    if (wave == 0) {
        float m = fmaxf(fmaxf(wmax[0][lane], wmax[1][lane]),
                        fmaxf(wmax[2][lane], wmax[3][lane]));
        atomicMax(&thr_raw[t * COUT + lane], enc_f(m));
    }
}

// ---------------------------------------------------------------------------
// Pass 2: sequential T-loop, conv RECOMPUTED per step (no i buffer).
// Block = one (b,h) row, 256 threads, LDS budget ~22 KB.
// Phase A (lane=channel): conv via LDS-broadcast x-tile -> sI[px][c] (pad 65).
// Phase B (thread=pixel, 4 ch-groups of 16): ASF/LIF from sI, WTA via local
// argmax + 4-entry LDS combine (r6-proven), coalesced direct spike stores.
// mem[16] per thread persists in registers across all t.
// Grid = B*H = 2048 blocks.
// ---------------------------------------------------------------------------
__global__ __launch_bounds__(256) void lif_kernel(
    const float* __restrict__ x,              // (T,B,3,64,64)
    const float* __restrict__ Wt,             // (64,3,3,3)
    const unsigned int* __restrict__ thr_raw, // (T,64)
    float* __restrict__ out)                  // (T,B,64,64,64)
{
    __shared__ float sx[CIN][3][68];          // 3 rows: h-1,h,h+1
    __shared__ float sI[64][65];              // conv result, pad-65
    __shared__ float sthr[COUT], sinv[COUT], s04[COUT], sinh_[COUT];
    __shared__ float sscore[4][64];
    __shared__ int   spack[4][64];

    const int tid  = threadIdx.x;
    const int lane = tid & 63;                // phase A: channel
    const int wave = tid >> 6;
    const int px   = tid & 63;                // phase B: pixel (w)
    const int grp  = tid >> 6;                // phase B: channel group
    const int b    = blockIdx.x >> 6;
    const int h    = blockIdx.x & 63;

    float w[27];
    #pragma unroll
    for (int k = 0; k < 27; k++) w[k] = Wt[lane * 27 + k];

    float mem[16];
    #pragma unroll
    for (int j = 0; j < 16; j++) mem[j] = 0.f;

    #pragma unroll 1
    for (int t = 0; t < TT; t++) {
        __syncthreads();   // prior-step LDS reads complete

        // ---- stage x rows h-1..h+1 (3 x 3 x 66) + threshold constants ----
        const float* xb = x + ((size_t)t * BB + b) * (CIN * HW);
        for (int l = tid; l < CIN * 3 * 66; l += 256) {
            int ci  = l / 198;
            int r   = (l % 198) / 66;
            int col = l % 66;
            int gh = h + r - 1;
            int gw = col - 1;
            float v = 0.f;
            if (gh >= 0 && gh < HH && gw >= 0 && gw < WW)
                v = xb[ci * HW + gh * WW + gw];
            sx[ci][r][col] = v;
        }
        if (tid < COUT) {
            float thr = dec_f(thr_raw[t * COUT + tid]) + 1e-4f;
            sthr[tid]  = thr;
            sinv[tid]  = 8.0f / thr;
            s04[tid]   = 0.4f * thr;
            sinh_[tid] = INH * thr;
        }
        __syncthreads();

        // ---- phase A: conv, lane=channel; each wave does its 16 pixels ----
        #pragma unroll
        for (int cc = 0; cc < 4; cc++) {
            const int base = wave * 16 + cc * 4;   // wave-uniform
            float acc0 = 0.f, acc1 = 0.f, acc2 = 0.f, acc3 = 0.f;
            #pragma unroll
            for (int ci = 0; ci < CIN; ci++)
                #pragma unroll
                for (int kh = 0; kh < 3; kh++) {
                    const float* rp = &sx[ci][kh][base];
                    float4 q  = *(const float4*)rp;
                    float2 r2 = *(const float2*)(rp + 4);
                    float x0 = q.x, x1 = q.y, x2 = q.z, x3 = q.w;
                    float x4 = r2.x, x5 = r2.y;
                    const float w0 = w[ci * 9 + kh * 3 + 0];
                    const float w1 = w[ci * 9 + kh * 3 + 1];
                    const float w2 = w[ci * 9 + kh * 3 + 2];
                    acc0 = fmaf(w0, x0, acc0); acc0 = fmaf(w1, x1, acc0); acc0 = fmaf(w2, x2, acc0);
                    acc1 = fmaf(w0, x1, acc1); acc1 = fmaf(w1, x2, acc1); acc1 = fmaf(w2, x3, acc1);
                    acc2 = fmaf(w0, x2, acc2); acc2 = fmaf(w1, x3, acc2); acc2 = fmaf(w2, x4, acc2);
                    acc3 = fmaf(w0, x3, acc3); acc3 = fmaf(w1, x4, acc3); acc3 = fmaf(w2, x5, acc3);
                }
            sI[base + 0][lane] = acc0;
            sI[base + 1][lane] = acc1;
            sI[base + 2][lane] = acc2;
            sI[base + 3][lane] = acc3;
        }
        __syncthreads();

        // ---- phase B: thread=pixel, 16 channels; ASF/LIF + local WTA ----
        float best = -INFINITY;
        int bch = 0, bsp = 0;
        #pragma unroll
        for (int j = 0; j < 16; j++) {
            const int c = grp * 16 + j;
            float iv  = sI[px][c];
            float cur = fmaxf(iv, 0.f);
            float z   = (cur - s04[c]) * sinv[c];
            float sig = 1.0f / (1.0f + expf(-z));
            float m   = mem[j] * DECAY + sthr[c] * sig;
            mem[j] = m;
            int   s     = m > sthr[c];
            float score = s ? m : 0.f;
            if (score > best) { best = score; bch = c; bsp = s; }
        }
        sscore[grp][px] = best;
        spack[grp][px]  = (bch << 1) | bsp;
        __syncthreads();

        // combine 4 group winners in ascending group order (first-argmax)
        float wbest = sscore[0][px];
        int   wp    = spack[0][px];
        #pragma unroll
        for (int g = 1; g < 4; g++) {
            float sc = sscore[g][px];
            int   pk = spack[g][px];
            if (sc > wbest) { wbest = sc; wp = pk; }
        }
        const int wwc = wp >> 1;
        const int wsp = wp & 1;

        // direct coalesced stores (lanes = consecutive px per channel)
        float* ob = out + (((size_t)t * BB + b) * COUT) * HW + h * WW;
        #pragma unroll
        for (int j = 0; j < 16; j++) {
            const int c = grp * 16 + j;
            int fired = (c == wwc) && wsp;
            ob[(size_t)c * HW + px] = fired ? 1.f : 0.f;
            mem[j] = fired ? 0.f : (mem[j] - (wsp ? sinh_[c] : 0.f));
        }
    }
}

// ---------------------------------------------------------------------------
extern "C" void kernel_launch(void* const* d_in, const int* in_sizes, int n_in,
                              void* d_out, int out_size, void* d_ws, size_t ws_size,
                              hipStream_t stream) {
    const float* x = (const float*)d_in[0];   // (T,B,3,64,64)
    const float* W = (const float*)d_in[1];   // (64,3,3,3)
    float* out     = (float*)d_out;           // (T,B,64,64,64)

    unsigned int* thr = (unsigned int*)d_ws;  // (T,64)
    hipMemsetAsync(thr, 0, TT * COUT * sizeof(unsigned int), stream);

    thr_kernel<<<dim3(HH / 4, BB, TT), 256, 0, stream>>>(x, W, thr);
    lif_kernel<<<dim3(BB * HH), 256, 0, stream>>>(x, W, thr, out);
}

// Round 10
// 556.913 us; speedup vs baseline: 1.3900x; 1.3900x over previous
//
#include <hip/hip_runtime.h>
#include <math.h>

#define TT 10
#define BB 32
#define CIN 3
#define COUT 64
#define HH 64
#define WW 64
#define HW (HH*WW)           // 4096
#define DECAY 0.2f
#define INH 1.625f
#define RS 68                // LDS row stride (floats): 272B, 16B-aligned

__device__ __forceinline__ unsigned int enc_f(float f) {
    unsigned int u = __float_as_uint(f);
    return (u & 0x80000000u) ? ~u : (u | 0x80000000u);
}
__device__ __forceinline__ float dec_f(unsigned int u) {
    u = (u & 0x80000000u) ? (u & 0x7FFFFFFFu) : ~u;
    return __uint_as_float(u);
}

// Stage NROWS rows of x into LDS rows of stride RS.
// Slot cl of a row holds x col (cl-1); cl==0 and cl>=65 are zero pad.
// Row r maps to (ci = r/RPC, gh = ghbase + r%RPC - 1). All global loads are
// issued before any LDS store (independent -> single latency exposure).
template <int NROWS, int RPC>
__device__ __forceinline__ void stage_x(float* sxf, const float* xb,
                                        int ghbase, int tid) {
    const int NSLOT = NROWS * RS;
    const int NITER = (NSLOT + 255) / 256;
    float vals[NITER];
    #pragma unroll
    for (int it = 0; it < NITER; it++) {
        int l = tid + it * 256;
        float v = 0.f;
        if (l < NSLOT) {
            int row = l / RS, cl = l % RS;
            int ci = row / RPC, rr = row % RPC;
            int gh = ghbase + rr - 1;
            if (cl >= 1 && cl <= 64 && gh >= 0 && gh < HH)
                v = xb[ci * HW + gh * WW + (cl - 1)];
        }
        vals[it] = v;
    }
    #pragma unroll
    for (int it = 0; it < NITER; it++) {
        int l = tid + it * 256;
        if (l < NSLOT) sxf[l] = vals[it];
    }
}

// Conv core: 16 pixels starting at p0 (16-aligned), lane = channel.
// rows = 9 LDS rows [(ci,kh) pairs] each of stride RS; row k starts at
// rows[k]*RS. Per row: 18 floats via 4xb128+b64 broadcast; 48 FMA over 16
// independent accs. fmaf order per pixel: k = ci*9+kh*3+kw ascending.
__device__ __forceinline__ void conv16(const float* __restrict__ sxbase,
                                       const int* rows, const float* w,
                                       int p0, float acc[16]) {
    #pragma unroll
    for (int j = 0; j < 16; j++) acc[j] = 0.f;
    #pragma unroll
    for (int q = 0; q < 9; q++) {            // q = ci*3 + kh
        const float* rp = sxbase + rows[q] * RS + p0;   // 16B-aligned
        float xr[18];
        float4 a0 = *(const float4*)(rp + 0);
        float4 a1 = *(const float4*)(rp + 4);
        float4 a2 = *(const float4*)(rp + 8);
        float4 a3 = *(const float4*)(rp + 12);
        float2 a4 = *(const float2*)(rp + 16);
        xr[0]=a0.x; xr[1]=a0.y; xr[2]=a0.z; xr[3]=a0.w;
        xr[4]=a1.x; xr[5]=a1.y; xr[6]=a1.z; xr[7]=a1.w;
        xr[8]=a2.x; xr[9]=a2.y; xr[10]=a2.z; xr[11]=a2.w;
        xr[12]=a3.x; xr[13]=a3.y; xr[14]=a3.z; xr[15]=a3.w;
        xr[16]=a4.x; xr[17]=a4.y;
        const float w0 = w[q * 3 + 0];
        const float w1 = w[q * 3 + 1];
        const float w2 = w[q * 3 + 2];
        #pragma unroll
        for (int j = 0; j < 16; j++) {
            acc[j] = fmaf(w0, xr[j],     acc[j]);
            acc[j] = fmaf(w1, xr[j + 1], acc[j]);
            acc[j] = fmaf(w2, xr[j + 2], acc[j]);
        }
    }
}

// ---------------------------------------------------------------------------
// Pass 1: thr[t][c] = max over (B,H,W) of conv. t-parallel.
// Block = (4-row group, b, t); wave = one row (4 chunks of 16 px).
// ---------------------------------------------------------------------------
__global__ __launch_bounds__(256) void thr_kernel(
    const float* __restrict__ x,        // (T,B,3,64,64)
    const float* __restrict__ Wt,       // (64,3,3,3)
    unsigned int* __restrict__ thr_raw) // (T,64) pre-zeroed
{
    __shared__ float sx[CIN * 6][RS];   // 6 rows per ci: h0-1 .. h0+4
    __shared__ float wmax[4][COUT];

    const int tid  = threadIdx.x;
    const int lane = tid & 63;          // channel
    const int wave = tid >> 6;          // row within 4-row group
    const int h0   = blockIdx.x * 4;
    const int b    = blockIdx.y;
    const int t    = blockIdx.z;

    float w[27];
    #pragma unroll
    for (int k = 0; k < 27; k++) w[k] = Wt[lane * 27 + k];

    const float* xb = x + ((size_t)t * BB + b) * (CIN * HW);
    stage_x<CIN * 6, 6>(&sx[0][0], xb, h0, tid);
    __syncthreads();

    // rows for this wave: (ci, wave+kh) -> ci*6 + wave + kh
    int rows[9];
    #pragma unroll
    for (int ci = 0; ci < CIN; ci++)
        #pragma unroll
        for (int kh = 0; kh < 3; kh++)
            rows[ci * 3 + kh] = ci * 6 + wave + kh;

    float mx = -INFINITY;
    #pragma unroll 1
    for (int cc = 0; cc < 4; cc++) {
        float acc[16];
        conv16(&sx[0][0], rows, w, cc * 16, acc);
        float m01 = fmaxf(fmaxf(acc[0], acc[1]), fmaxf(acc[2], acc[3]));
        float m23 = fmaxf(fmaxf(acc[4], acc[5]), fmaxf(acc[6], acc[7]));
        float m45 = fmaxf(fmaxf(acc[8], acc[9]), fmaxf(acc[10], acc[11]));
        float m67 = fmaxf(fmaxf(acc[12], acc[13]), fmaxf(acc[14], acc[15]));
        mx = fmaxf(mx, fmaxf(fmaxf(m01, m23), fmaxf(m45, m67)));
    }

    wmax[wave][lane] = mx;
    __syncthreads();
    if (wave == 0) {
        float m = fmaxf(fmaxf(wmax[0][lane], wmax[1][lane]),
                        fmaxf(wmax[2][lane], wmax[3][lane]));
        atomicMax(&thr_raw[t * COUT + lane], enc_f(m));
    }
}

// ---------------------------------------------------------------------------
// Pass 2: sequential T-loop, conv recomputed per step (no i buffer).
// Block = one (b,h) row; wave = 16 px, lane = channel, mem[16] in registers.
// Single phase: conv16 -> ASF/LIF -> ballot-gated wave WTA -> wave-local
// stores (no cross-wave data flow; 2 barriers/t protect only sx).
// ---------------------------------------------------------------------------
__global__ __launch_bounds__(256) void lif_kernel(
    const float* __restrict__ x,              // (T,B,3,64,64)
    const float* __restrict__ Wt,             // (64,3,3,3)
    const unsigned int* __restrict__ thr_raw, // (T,64)
    float* __restrict__ out)                  // (T,B,64,64,64)
{
    __shared__ float sx[CIN * 3][RS];         // 3 rows per ci: h-1,h,h+1

    const int tid  = threadIdx.x;
    const int lane = tid & 63;                // channel
    const int wave = tid >> 6;
    const int p0   = __builtin_amdgcn_readfirstlane(wave * 16);
    const int b    = blockIdx.x >> 6;
    const int h    = blockIdx.x & 63;

    float w[27];
    #pragma unroll
    for (int k = 0; k < 27; k++) w[k] = Wt[lane * 27 + k];

    int rows[9];
    #pragma unroll
    for (int q = 0; q < 9; q++) rows[q] = q;  // (ci,kh) -> ci*3+kh

    float mem[16];
    #pragma unroll
    for (int j = 0; j < 16; j++) mem[j] = 0.f;

    #pragma unroll 1
    for (int t = 0; t < TT; t++) {
        __syncthreads();   // all conv reads of prior sx complete

        const float* xb = x + ((size_t)t * BB + b) * (CIN * HW);
        stage_x<CIN * 3, 3>(&sx[0][0], xb, h, tid);

        // per-lane (= per-channel) threshold constants
        float thr   = dec_f(thr_raw[t * COUT + lane]) + 1e-4f;
        float sinv  = 8.0f / thr;
        float s04   = 0.4f * thr;
        float sinh_ = INH * thr;
        __syncthreads();

        float acc[16];
        conv16(&sx[0][0], rows, w, p0, acc);

        int fmask = 0, amask = 0;   // fired / any-spike per pixel j
        #pragma unroll
        for (int j = 0; j < 16; j++) {
            float cur = fmaxf(acc[j], 0.f);
            float z   = (cur - s04) * sinv;
            float sig = 1.0f / (1.0f + expf(-z));
            float m   = mem[j] * DECAY + thr * sig;
            int   sp  = m > thr;
            float score = sp ? m : 0.f;

            unsigned long long blt = __ballot(sp);
            int fr = 0, sp_any = 0;
            if (blt) {   // wave-uniform, rare
                float bs = score;
                int   bc = lane;
                #pragma unroll
                for (int off = 32; off > 0; off >>= 1) {
                    float so = __shfl_xor(bs, off, 64);
                    int   co = __shfl_xor(bc, off, 64);
                    if (so > bs || (so == bs && co < bc)) { bs = so; bc = co; }
                }
                sp_any = __shfl(sp, bc, 64);   // winner's spike = any_sp
                fr     = (lane == bc) && sp;
            }
            mem[j] = fr ? 0.f : (m - (sp_any ? sinh_ : 0.f));
            if (fr) fmask |= (1 << j);
            if (sp_any) amask |= (1 << j);
        }

        // wave-local stores: lane's channel row, its 16 px, 4x dwordx4.
        // Each lane writes one full 64B line (L2 write-combines).
        float* ob = out + (((size_t)t * BB + b) * COUT + lane) * HW
                        + h * WW + p0;
        #pragma unroll
        for (int g = 0; g < 4; g++) {
            float4 v;
            v.x = (fmask >> (g * 4 + 0)) & 1 ? 1.f : 0.f;
            v.y = (fmask >> (g * 4 + 1)) & 1 ? 1.f : 0.f;
            v.z = (fmask >> (g * 4 + 2)) & 1 ? 1.f : 0.f;
            v.w = (fmask >> (g * 4 + 3)) & 1 ? 1.f : 0.f;
            *(float4*)(ob + g * 4) = v;
        }
    }
}

// ---------------------------------------------------------------------------
extern "C" void kernel_launch(void* const* d_in, const int* in_sizes, int n_in,
                              void* d_out, int out_size, void* d_ws, size_t ws_size,
                              hipStream_t stream) {
    const float* x = (const float*)d_in[0];   // (T,B,3,64,64)
    const float* W = (const float*)d_in[1];   // (64,3,3,3)
    float* out     = (float*)d_out;           // (T,B,64,64,64)

    unsigned int* thr = (unsigned int*)d_ws;  // (T,64)
    hipMemsetAsync(thr, 0, TT * COUT * sizeof(unsigned int), stream);

    thr_kernel<<<dim3(HH / 4, BB, TT), 256, 0, stream>>>(x, W, thr);
    lif_kernel<<<dim3(BB * HH), 256, 0, stream>>>(x, W, thr, out);
}